// Round 2
// baseline (569.533 us; speedup 1.0000x reference)
//
#include <hip/hip_runtime.h>

typedef __bf16 bf16;
typedef __attribute__((ext_vector_type(4))) float f32x4;
typedef __attribute__((ext_vector_type(8))) __bf16 bf16x8;
typedef __attribute__((ext_vector_type(4))) __bf16 bf16x4;
typedef __attribute__((ext_vector_type(4))) int i32x4;

#define NN 8192
#define FI 512
#define FO 256
#define NSPLIT 4
#define JCHUNK (NN / NSPLIT)

// ---------------------------------------------------------------------------
// kw: W [512][256] f32 -> Wt_hi/Wt_lo [256][512] bf16 (transposed + split),
// so k1 can load B fragments straight from global (bf16x8 per lane).
// ---------------------------------------------------------------------------
__global__ __launch_bounds__(256) void kw_split(const float* __restrict__ W,
                                                bf16* __restrict__ wth,
                                                bf16* __restrict__ wtl) {
  const int idx = blockIdx.x * 256 + threadIdx.x;  // 512*256 = 131072
  const int k = idx >> 8, n = idx & 255;
  float x = W[idx];
  bf16 hi = (bf16)x;
  wth[(size_t)n * FI + k] = hi;
  wtl[(size_t)n * FI + k] = (bf16)(x - (float)hi);
}

// ---------------------------------------------------------------------------
// k1: Wh = h @ W + bW via split-bf16 MFMA (hi*hi + hi*lo + lo*hi, fp32 acc).
// BARRIER-FREE main loop: each wave owns 16 rows x 128 cols; the A fragment
// (lane (m16,q) holds h[row=m16][k=q*8..+7]) is loaded directly from global
// (32B/lane) and hi/lo-split in registers -- no LDS staging, no syncthreads.
// Epilogue: whb staged through LDS once so the global store is a single
// fully-coalesced 16 KB linear block per workgroup (old path: 2B stores at
// 64B stride). f1/f2 via shfl-reduce + atomicAdd (2 waves per row).
// Grid 256 blocks (BM=32, n split across wave pairs).
// ---------------------------------------------------------------------------
__global__ __launch_bounds__(256) void k1_gemm(
    const float* __restrict__ h, const bf16* __restrict__ wth,
    const bf16* __restrict__ wtl, const float* __restrict__ bW,
    const float* __restrict__ a1, const float* __restrict__ a2,
    bf16* __restrict__ whb, float* __restrict__ f1, float* __restrict__ f2) {
  __shared__ bf16 stg[32 * 256];  // [n][il], 16 KB
  const int t = threadIdx.x;
  const int lane = t & 63, w = t >> 6;
  const int m16 = lane & 15, q = lane >> 4;
  const int wr = w & 1, wn = w >> 1;
  const int rb = blockIdx.x;
  const int row = rb * 32 + wr * 16 + m16;  // A-fragment row for this lane
  const int nb = wn * 128;

  const f32x4 z4 = {0.f, 0.f, 0.f, 0.f};
  f32x4 acc[8];
#pragma unroll
  for (int nn = 0; nn < 8; ++nn) acc[nn] = z4;

  const float* hrow = h + (size_t)row * FI + q * 8;
  const bf16* wthp = wth + (size_t)(nb + m16) * FI + q * 8;
  const bf16* wtlp = wtl + (size_t)(nb + m16) * FI + q * 8;

  for (int kt = 0; kt < FI / 32; ++kt) {
    f32x4 h0 = *(const f32x4*)(hrow + kt * 32);
    f32x4 h1 = *(const f32x4*)(hrow + kt * 32 + 4);
    bf16x8 hh, hl;
#pragma unroll
    for (int x = 0; x < 4; ++x) {
      float v = h0[x];
      bf16 hi = (bf16)v;
      hh[x] = hi;
      hl[x] = (bf16)(v - (float)hi);
      float v2 = h1[x];
      bf16 hi2 = (bf16)v2;
      hh[4 + x] = hi2;
      hl[4 + x] = (bf16)(v2 - (float)hi2);
    }
#pragma unroll
    for (int nn = 0; nn < 8; ++nn) {
      const size_t woff = (size_t)(nn * 16) * FI + kt * 32;
      bf16x8 bh = *(const bf16x8*)(wthp + woff);
      bf16x8 bl = *(const bf16x8*)(wtlp + woff);
      acc[nn] = __builtin_amdgcn_mfma_f32_16x16x32_bf16(hh, bh, acc[nn], 0, 0, 0);
      acc[nn] = __builtin_amdgcn_mfma_f32_16x16x32_bf16(hl, bh, acc[nn], 0, 0, 0);
      acc[nn] = __builtin_amdgcn_mfma_f32_16x16x32_bf16(hh, bl, acc[nn], 0, 0, 0);
    }
  }
  // Epilogue. C/D layout: col = lane&15 (n), row = q*4+reg (i within 16-tile).
  float f1p[4] = {}, f2p[4] = {};
  const int il = wr * 16 + q * 4;
#pragma unroll
  for (int nn = 0; nn < 8; ++nn) {
    const int n = nb + nn * 16 + m16;
    const float bw = bW[n], av1 = a1[n], av2 = a2[n];
#pragma unroll
    for (int reg = 0; reg < 4; ++reg) {
      float wh = acc[nn][reg] + bw;
      stg[n * 32 + il + reg] = (bf16)wh;
      f1p[reg] += wh * av1;
      f2p[reg] += wh * av2;
    }
  }
#pragma unroll
  for (int m = 1; m < 16; m <<= 1) {
#pragma unroll
    for (int reg = 0; reg < 4; ++reg) {
      f1p[reg] += __shfl_xor(f1p[reg], m);
      f2p[reg] += __shfl_xor(f2p[reg], m);
    }
  }
  if (m16 == 0) {
#pragma unroll
    for (int reg = 0; reg < 4; ++reg) {
      const int i = rb * 32 + wr * 16 + q * 4 + reg;
      atomicAdd(&f1[i], f1p[reg]);
      atomicAdd(&f2[i], f2p[reg]);
    }
  }
  __syncthreads();
  // Coalesced whb store: block region is 8192 contiguous bf16 (16 KB).
  bf16x8* dst = (bf16x8*)(whb + (size_t)rb * (FO * 32));
  const bf16x8* srcv = (const bf16x8*)stg;
#pragma unroll
  for (int u = 0; u < 4; ++u) dst[t * 4 + u] = srcv[t * 4 + u];
}

// ---------------------------------------------------------------------------
// k4: fused masked-softmax GEMM partial (j-split x NSPLIT), adj read fused.
// BARRIER-FREE: the P tile never touches LDS. Each lane computes the MFMA
// A-fragment it owns directly: row = m16 (of the wave's 16-row tile),
// j = q*8..+7 of the 32-wide k-step. Waves 0/1 take row-halves, waves 2/3
// repeat them for the other n-half (scores duplicated x2; adj duplicate
// reads are L1 hits). adj + f2 for the next k-step are explicitly
// prefetched so each wave keeps ~2 KB of HBM traffic in flight with no
// vmcnt(0) drain anywhere in the loop.
// Softmax shift: sh = lrelu(ci + 8) >= row max (|f2| << 8); cancels in acc/l.
// Grid (256, NSPLIT) = 1024 blocks -> 4/CU, 16 waves/CU.
// ---------------------------------------------------------------------------
__global__ __launch_bounds__(256, 4) void k4_attn(
    const int* __restrict__ adj, const bf16* __restrict__ whb,
    const float* __restrict__ f1, const float* __restrict__ f2,
    const float* __restrict__ ba_p,
    float* __restrict__ acc_part, float* __restrict__ l_part) {
  const int t = threadIdx.x;
  const int lane = t & 63, w = t >> 6;
  const int m16 = lane & 15, q = lane >> 4;
  const int wr = w & 1, wn = w >> 1;
  const int rb = blockIdx.x, s = blockIdx.y;
  const int i0 = rb * 32;
  const int row = i0 + wr * 16 + m16;  // score/A-fragment row for this lane

  const float ba = *ba_p;
  const float ci = f1[row] + ba;
  const float arg0 = ci + 8.0f;
  const float sh = fmaxf(arg0, 0.2f * arg0);

  const f32x4 z4 = {0.f, 0.f, 0.f, 0.f};
  f32x4 acc[8];
#pragma unroll
  for (int nn = 0; nn < 8; ++nn) acc[nn] = z4;
  float lreg = 0.f;

  const int sbase = s * JCHUNK;
  const int* arow = adj + (size_t)row * NN + sbase + q * 8;
  const float* frow = f2 + sbase + q * 8;
  const bf16* bptr = whb + (size_t)(sbase >> 5) * (FO * 32) +
                     (size_t)(wn * 128 + m16) * 32 + q * 8;

  i32x4 na0 = *(const i32x4*)(arow);
  i32x4 na1 = *(const i32x4*)(arow + 4);
  f32x4 nf0 = *(const f32x4*)(frow);
  f32x4 nf1 = *(const f32x4*)(frow + 4);

  const int KT = JCHUNK / 32;
  for (int kt = 0; kt < KT; ++kt) {
    const i32x4 ca0 = na0;
    const i32x4 ca1 = na1;
    const f32x4 cf0 = nf0;
    const f32x4 cf1 = nf1;
    if (kt + 1 < KT) {  // prefetch next k-step (wave-uniform branch)
      na0 = *(const i32x4*)(arow + (kt + 1) * 32);
      na1 = *(const i32x4*)(arow + (kt + 1) * 32 + 4);
      nf0 = *(const f32x4*)(frow + (kt + 1) * 32);
      nf1 = *(const f32x4*)(frow + (kt + 1) * 32 + 4);
    }
    float pv[8];
#pragma unroll
    for (int x = 0; x < 4; ++x) {
      float arg = ci + cf0[x];
      float e = fmaxf(arg, 0.2f * arg);
      pv[x] = (ca0[x] > 0) ? __expf(e - sh) : 0.f;
      float arg2 = ci + cf1[x];
      float e2 = fmaxf(arg2, 0.2f * arg2);
      pv[4 + x] = (ca1[x] > 0) ? __expf(e2 - sh) : 0.f;
    }
    bf16x8 af;
#pragma unroll
    for (int x = 0; x < 8; ++x) {
      lreg += pv[x];
      af[x] = (bf16)pv[x];
    }
    const bf16* bk = bptr + (size_t)kt * (FO * 32);
#pragma unroll
    for (int nn = 0; nn < 8; ++nn) {
      bf16x8 bfr = *(const bf16x8*)(bk + nn * (16 * 32));
      acc[nn] = __builtin_amdgcn_mfma_f32_16x16x32_bf16(af, bfr, acc[nn], 0, 0, 0);
    }
  }
  // l row-sum: 4 q-lanes share a row; n-half waves hold identical lreg.
  lreg += __shfl_xor(lreg, 16);
  lreg += __shfl_xor(lreg, 32);
  if (q == 0 && wn == 0) l_part[(size_t)s * NN + row] = lreg;
  // C/D: col = lane&15 (n), row = q*4+reg
  float* ap = acc_part + (size_t)s * ((size_t)NN * FO);
  const int r0 = i0 + wr * 16 + q * 4;
#pragma unroll
  for (int nn = 0; nn < 8; ++nn) {
    const int n = wn * 128 + nn * 16 + m16;
#pragma unroll
    for (int reg = 0; reg < 4; ++reg) {
      ap[(size_t)(r0 + reg) * FO + n] = acc[nn][reg];
    }
  }
}

// ---------------------------------------------------------------------------
// k5: out[i][n] = (sum_s acc_part[s][i][n]) / (sum_s l_part[s][i])
// ---------------------------------------------------------------------------
__global__ __launch_bounds__(256) void k5_reduce(
    const float* __restrict__ accp, const float* __restrict__ lp,
    float* __restrict__ out) {
  const int idx = blockIdx.x * 256 + threadIdx.x;
  const int i = idx >> 6, n4 = (idx & 63) * 4;
  f32x4 sum = {0.f, 0.f, 0.f, 0.f};
  float l = 0.f;
#pragma unroll
  for (int s = 0; s < NSPLIT; ++s) {
    sum += *(const f32x4*)&accp[(size_t)s * ((size_t)NN * FO) + (size_t)i * FO + n4];
    l += lp[s * NN + i];
  }
  const float rl = 1.0f / l;
  f32x4 o = sum * rl;
  *(f32x4*)&out[(size_t)i * FO + n4] = o;
}

// ---------------------------------------------------------------------------
// Workspace layout:
//   [0, 4MB)        whb  (bf16 Wh, fragment-major)
//   4MB             f1   (32 KB)
//   +32KB           f2   (32 KB)
//   4MB+64KB        acc_part[4][8192][256] f32 (32 MB)
//   +...            l_part[4][8192] f32 (128 KB)
//   +...            wth (256 KB), wtl (256 KB)
// total ~36.9 MB
// ---------------------------------------------------------------------------
extern "C" void kernel_launch(void* const* d_in, const int* in_sizes, int n_in,
                              void* d_out, int out_size, void* d_ws, size_t ws_size,
                              hipStream_t stream) {
  const float* h   = (const float*)d_in[0];
  const int*   adj = (const int*)d_in[1];
  const float* W   = (const float*)d_in[2];
  const float* bW  = (const float*)d_in[3];
  const float* a1  = (const float*)d_in[4];
  const float* a2  = (const float*)d_in[5];
  const float* ba  = (const float*)d_in[6];
  float* out = (float*)d_out;

  char* ws = (char*)d_ws;
  bf16* whb   = (bf16*)ws;
  float* f1   = (float*)(ws + 4u * 1024 * 1024);
  float* f2   = (float*)(ws + 4u * 1024 * 1024 + 32 * 1024);
  float* accp = (float*)(ws + 4u * 1024 * 1024 + 64 * 1024);
  float* lp   = accp + (size_t)NSPLIT * NN * FO;
  bf16* wth   = (bf16*)((char*)lp + (size_t)NSPLIT * NN * 4);
  bf16* wtl   = wth + (size_t)FO * FI;

  hipMemsetAsync(f1, 0, 64 * 1024, stream);  // zero f1+f2 (atomic targets)

  kw_split<<<FI * FO / 256, 256, 0, stream>>>(W, wth, wtl);
  k1_gemm<<<NN / 32, 256, 0, stream>>>(h, wth, wtl, bW, a1, a2, whb, f1, f2);
  k4_attn<<<dim3(NN / 32, NSPLIT), 256, 0, stream>>>(adj, whb, f1, f2, ba, accp, lp);
  k5_reduce<<<(NN * FO / 4) / 256, 256, 0, stream>>>(accp, lp, out);
}

// Round 3
// 558.974 us; speedup vs baseline: 1.0189x; 1.0189x over previous
//
#include <hip/hip_runtime.h>

typedef __bf16 bf16;
typedef __attribute__((ext_vector_type(4))) float f32x4;
typedef __attribute__((ext_vector_type(8))) __bf16 bf16x8;
typedef __attribute__((ext_vector_type(4))) __bf16 bf16x4;
typedef __attribute__((ext_vector_type(4))) int i32x4;

#define NN 8192
#define FI 512
#define FO 256
#define NSPLIT 4
#define JCHUNK (NN / NSPLIT)

// ---------------------------------------------------------------------------
// kw: W [512][256] f32 -> Wt_hi/Wt_lo [256][512] bf16 (transposed + split),
// so k1 can load B fragments straight from global (bf16x8 per lane).
// ---------------------------------------------------------------------------
__global__ __launch_bounds__(256) void kw_split(const float* __restrict__ W,
                                                bf16* __restrict__ wth,
                                                bf16* __restrict__ wtl) {
  const int idx = blockIdx.x * 256 + threadIdx.x;  // 512*256 = 131072
  const int k = idx >> 8, n = idx & 255;
  float x = W[idx];
  bf16 hi = (bf16)x;
  wth[(size_t)n * FI + k] = hi;
  wtl[(size_t)n * FI + k] = (bf16)(x - (float)hi);
}

// ---------------------------------------------------------------------------
// k1: Wh = h @ W + bW via split-bf16 MFMA (hi*hi + hi*lo + lo*hi, fp32 acc).
// Barrier-free main loop; wave = 16 rows x 64 cols (acc[4]). Per k-step the
// 8 B fragments (bh/bl x4) are loaded into register ARRAYS first (8 loads in
// flight -- round-2 regression was the compiler serializing interleaved
// load+mfma at 48 VGPRs), then h is split hi/lo, then 12 MFMAs. h prefetched
// one kt ahead. Grid (256,2) = 512 blocks -> 2 blocks/CU, 2 waves/SIMD.
// Epilogue: whb staged through LDS once -> one coalesced 8 KB linear store
// per block; f1/f2 via shfl-reduce + atomicAdd.
// ---------------------------------------------------------------------------
__global__ __launch_bounds__(256, 2) void k1_gemm(
    const float* __restrict__ h, const bf16* __restrict__ wth,
    const bf16* __restrict__ wtl, const float* __restrict__ bW,
    const float* __restrict__ a1, const float* __restrict__ a2,
    bf16* __restrict__ whb, float* __restrict__ f1, float* __restrict__ f2) {
  __shared__ bf16 stg[128 * 32];  // [n_local][il], 8 KB
  const int t = threadIdx.x;
  const int lane = t & 63, w = t >> 6;
  const int m16 = lane & 15, q = lane >> 4;
  const int wr = w & 1, wn = w >> 1;
  const int rb = blockIdx.x, bj = blockIdx.y;
  const int row = rb * 32 + wr * 16 + m16;  // A-fragment row for this lane
  const int nb = bj * 128 + wn * 64;

  const f32x4 z4 = {0.f, 0.f, 0.f, 0.f};
  f32x4 acc[4];
#pragma unroll
  for (int nn = 0; nn < 4; ++nn) acc[nn] = z4;

  const float* hrow = h + (size_t)row * FI + q * 8;
  const bf16* wthp = wth + (size_t)(nb + m16) * FI + q * 8;
  const bf16* wtlp = wtl + (size_t)(nb + m16) * FI + q * 8;

  f32x4 nh0 = *(const f32x4*)(hrow);
  f32x4 nh1 = *(const f32x4*)(hrow + 4);

  const int KT = FI / 32;
  for (int kt = 0; kt < KT; ++kt) {
    // B fragments for this kt: all 8 loads issued back-to-back (stay in flight)
    bf16x8 bh[4], bl[4];
#pragma unroll
    for (int nn = 0; nn < 4; ++nn) {
      const size_t woff = (size_t)(nn * 16) * FI + kt * 32;
      bh[nn] = *(const bf16x8*)(wthp + woff);
      bl[nn] = *(const bf16x8*)(wtlp + woff);
    }
    const f32x4 h0 = nh0, h1 = nh1;
    const int ktn = (kt + 1 < KT) ? kt + 1 : kt;
    nh0 = *(const f32x4*)(hrow + ktn * 32);
    nh1 = *(const f32x4*)(hrow + ktn * 32 + 4);
    bf16x8 hh, hl;
#pragma unroll
    for (int x = 0; x < 4; ++x) {
      float v = h0[x];
      bf16 hi = (bf16)v;
      hh[x] = hi;
      hl[x] = (bf16)(v - (float)hi);
      float v2 = h1[x];
      bf16 hi2 = (bf16)v2;
      hh[4 + x] = hi2;
      hl[4 + x] = (bf16)(v2 - (float)hi2);
    }
#pragma unroll
    for (int nn = 0; nn < 4; ++nn) {
      acc[nn] = __builtin_amdgcn_mfma_f32_16x16x32_bf16(hh, bh[nn], acc[nn], 0, 0, 0);
      acc[nn] = __builtin_amdgcn_mfma_f32_16x16x32_bf16(hl, bh[nn], acc[nn], 0, 0, 0);
      acc[nn] = __builtin_amdgcn_mfma_f32_16x16x32_bf16(hh, bl[nn], acc[nn], 0, 0, 0);
    }
  }
  // Epilogue. C/D layout: col = lane&15 (n), row = q*4+reg (i within 16-tile).
  float f1p[4] = {}, f2p[4] = {};
  const int il = wr * 16 + q * 4;
#pragma unroll
  for (int nn = 0; nn < 4; ++nn) {
    const int n = nb + nn * 16 + m16;
    const int nl = wn * 64 + nn * 16 + m16;  // local n within block (0..127)
    const float bw = bW[n], av1 = a1[n], av2 = a2[n];
    bf16x4 st;
#pragma unroll
    for (int reg = 0; reg < 4; ++reg) {
      float wh = acc[nn][reg] + bw;
      st[reg] = (bf16)wh;
      f1p[reg] += wh * av1;
      f2p[reg] += wh * av2;
    }
    *(bf16x4*)&stg[nl * 32 + il] = st;
  }
#pragma unroll
  for (int m = 1; m < 16; m <<= 1) {
#pragma unroll
    for (int reg = 0; reg < 4; ++reg) {
      f1p[reg] += __shfl_xor(f1p[reg], m);
      f2p[reg] += __shfl_xor(f2p[reg], m);
    }
  }
  if (m16 == 0) {
#pragma unroll
    for (int reg = 0; reg < 4; ++reg) {
      const int i = rb * 32 + wr * 16 + q * 4 + reg;
      atomicAdd(&f1[i], f1p[reg]);
      atomicAdd(&f2[i], f2p[reg]);
    }
  }
  __syncthreads();
  // Coalesced whb store: block region is 4096 contiguous bf16 (8 KB).
  bf16x8* dst = (bf16x8*)(whb + (size_t)rb * (FO * 32) + (size_t)bj * (128 * 32));
  const bf16x8* srcv = (const bf16x8*)stg;
#pragma unroll
  for (int u = 0; u < 2; ++u) dst[t * 2 + u] = srcv[t * 2 + u];
}

// ---------------------------------------------------------------------------
// k4: fused masked-softmax GEMM partial (j-split x NSPLIT), adj read fused.
// Barrier-free; P never touches LDS (lane (m16,q) holds A-frag row=m16,
// j=q*8..+7 directly). Per k-step: (1) all 8 B fragments loaded into a
// register array -- 8 loads in flight, consumed only after the score phase
// (~150 cyc of VALU) so L2 latency is hidden; (2) adj/f2 prefetched one
// kt ahead (branchless clamped index keeps one basic block); (3) scores;
// (4) 8 MFMAs. Waves 0/1 = row halves, waves 2/3 repeat scores for the
// other n-half (adj re-reads hit L1/L2 -- FETCH_SIZE showed no extra HBM).
// Softmax shift: sh = lrelu(ci + 8) >= row max (|f2| << 8); cancels in acc/l.
// Grid (256, NSPLIT) = 1024 blocks -> 4/CU, 4 waves/SIMD.
// ---------------------------------------------------------------------------
__global__ __launch_bounds__(256, 4) void k4_attn(
    const int* __restrict__ adj, const bf16* __restrict__ whb,
    const float* __restrict__ f1, const float* __restrict__ f2,
    const float* __restrict__ ba_p,
    float* __restrict__ acc_part, float* __restrict__ l_part) {
  const int t = threadIdx.x;
  const int lane = t & 63, w = t >> 6;
  const int m16 = lane & 15, q = lane >> 4;
  const int wr = w & 1, wn = w >> 1;
  const int rb = blockIdx.x, s = blockIdx.y;
  const int i0 = rb * 32;
  const int row = i0 + wr * 16 + m16;  // score/A-fragment row for this lane

  const float ba = *ba_p;
  const float ci = f1[row] + ba;
  const float arg0 = ci + 8.0f;
  const float sh = fmaxf(arg0, 0.2f * arg0);

  const f32x4 z4 = {0.f, 0.f, 0.f, 0.f};
  f32x4 acc[8];
#pragma unroll
  for (int nn = 0; nn < 8; ++nn) acc[nn] = z4;
  float lreg = 0.f;

  const int sbase = s * JCHUNK;
  const int* arow = adj + (size_t)row * NN + sbase + q * 8;
  const float* frow = f2 + sbase + q * 8;
  const bf16* bptr = whb + (size_t)(sbase >> 5) * (FO * 32) +
                     (size_t)(wn * 128 + m16) * 32 + q * 8;

  i32x4 na0 = *(const i32x4*)(arow);
  i32x4 na1 = *(const i32x4*)(arow + 4);
  f32x4 nf0 = *(const f32x4*)(frow);
  f32x4 nf1 = *(const f32x4*)(frow + 4);

  const int KT = JCHUNK / 32;
  for (int kt = 0; kt < KT; ++kt) {
    // (1) B fragments for this kt: 8 loads issued back-to-back, in flight
    // until the MFMAs below.
    bf16x8 cb[8];
    const bf16* bk = bptr + (size_t)kt * (FO * 32);
#pragma unroll
    for (int nn = 0; nn < 8; ++nn)
      cb[nn] = *(const bf16x8*)(bk + nn * (16 * 32));
    const i32x4 ca0 = na0;
    const i32x4 ca1 = na1;
    const f32x4 cf0 = nf0;
    const f32x4 cf1 = nf1;
    // (2) prefetch next k-step adj/f2 (clamped index -> single basic block)
    const int ktn = (kt + 1 < KT) ? kt + 1 : kt;
    na0 = *(const i32x4*)(arow + ktn * 32);
    na1 = *(const i32x4*)(arow + ktn * 32 + 4);
    nf0 = *(const f32x4*)(frow + ktn * 32);
    nf1 = *(const f32x4*)(frow + ktn * 32 + 4);
    // (3) scores (register-only VALU; hides B-load latency)
    float pv[8];
#pragma unroll
    for (int x = 0; x < 4; ++x) {
      float arg = ci + cf0[x];
      float e = fmaxf(arg, 0.2f * arg);
      pv[x] = (ca0[x] > 0) ? __expf(e - sh) : 0.f;
      float arg2 = ci + cf1[x];
      float e2 = fmaxf(arg2, 0.2f * arg2);
      pv[4 + x] = (ca1[x] > 0) ? __expf(e2 - sh) : 0.f;
    }
    bf16x8 af;
#pragma unroll
    for (int x = 0; x < 8; ++x) {
      lreg += pv[x];
      af[x] = (bf16)pv[x];
    }
    // (4) MFMAs
#pragma unroll
    for (int nn = 0; nn < 8; ++nn)
      acc[nn] = __builtin_amdgcn_mfma_f32_16x16x32_bf16(af, cb[nn], acc[nn], 0, 0, 0);
  }
  // l row-sum: 4 q-lanes share a row; n-half waves hold identical lreg.
  lreg += __shfl_xor(lreg, 16);
  lreg += __shfl_xor(lreg, 32);
  if (q == 0 && wn == 0) l_part[(size_t)s * NN + row] = lreg;
  // C/D: col = lane&15 (n), row = q*4+reg
  float* ap = acc_part + (size_t)s * ((size_t)NN * FO);
  const int r0 = i0 + wr * 16 + q * 4;
#pragma unroll
  for (int nn = 0; nn < 8; ++nn) {
    const int n = wn * 128 + nn * 16 + m16;
#pragma unroll
    for (int reg = 0; reg < 4; ++reg) {
      ap[(size_t)(r0 + reg) * FO + n] = acc[nn][reg];
    }
  }
}

// ---------------------------------------------------------------------------
// k5: out[i][n] = (sum_s acc_part[s][i][n]) / (sum_s l_part[s][i])
// ---------------------------------------------------------------------------
__global__ __launch_bounds__(256) void k5_reduce(
    const float* __restrict__ accp, const float* __restrict__ lp,
    float* __restrict__ out) {
  const int idx = blockIdx.x * 256 + threadIdx.x;
  const int i = idx >> 6, n4 = (idx & 63) * 4;
  f32x4 sum = {0.f, 0.f, 0.f, 0.f};
  float l = 0.f;
#pragma unroll
  for (int s = 0; s < NSPLIT; ++s) {
    sum += *(const f32x4*)&accp[(size_t)s * ((size_t)NN * FO) + (size_t)i * FO + n4];
    l += lp[s * NN + i];
  }
  const float rl = 1.0f / l;
  f32x4 o = sum * rl;
  *(f32x4*)&out[(size_t)i * FO + n4] = o;
}

// ---------------------------------------------------------------------------
// Workspace layout:
//   [0, 4MB)        whb  (bf16 Wh, fragment-major)
//   4MB             f1   (32 KB)
//   +32KB           f2   (32 KB)
//   4MB+64KB        acc_part[4][8192][256] f32 (32 MB)
//   +...            l_part[4][8192] f32 (128 KB)
//   +...            wth (256 KB), wtl (256 KB)
// total ~36.9 MB
// ---------------------------------------------------------------------------
extern "C" void kernel_launch(void* const* d_in, const int* in_sizes, int n_in,
                              void* d_out, int out_size, void* d_ws, size_t ws_size,
                              hipStream_t stream) {
  const float* h   = (const float*)d_in[0];
  const int*   adj = (const int*)d_in[1];
  const float* W   = (const float*)d_in[2];
  const float* bW  = (const float*)d_in[3];
  const float* a1  = (const float*)d_in[4];
  const float* a2  = (const float*)d_in[5];
  const float* ba  = (const float*)d_in[6];
  float* out = (float*)d_out;

  char* ws = (char*)d_ws;
  bf16* whb   = (bf16*)ws;
  float* f1   = (float*)(ws + 4u * 1024 * 1024);
  float* f2   = (float*)(ws + 4u * 1024 * 1024 + 32 * 1024);
  float* accp = (float*)(ws + 4u * 1024 * 1024 + 64 * 1024);
  float* lp   = accp + (size_t)NSPLIT * NN * FO;
  bf16* wth   = (bf16*)((char*)lp + (size_t)NSPLIT * NN * 4);
  bf16* wtl   = wth + (size_t)FO * FI;

  hipMemsetAsync(f1, 0, 64 * 1024, stream);  // zero f1+f2 (atomic targets)

  kw_split<<<FI * FO / 256, 256, 0, stream>>>(W, wth, wtl);
  k1_gemm<<<dim3(NN / 32, 2), 256, 0, stream>>>(h, wth, wtl, bW, a1, a2, whb, f1, f2);
  k4_attn<<<dim3(NN / 32, NSPLIT), 256, 0, stream>>>(adj, whb, f1, f2, ba, accp, lp);
  k5_reduce<<<(NN * FO / 4) / 256, 256, 0, stream>>>(accp, lp, out);
}